// Round 3
// baseline (85.218 us; speedup 1.0000x reference)
//
#include <hip/hip_runtime.h>
#include <stdint.h>
#include <math.h>

#define ROWS 4096
#define COLS 11008
#define GRP  128
#define GPR  (COLS / GRP)   // 86 groups per row

// ---------------------------------------------------------------------------
// Kernel 1: build jgrp[k] = invcol[k] >> 7  (uint8, 0..85) into d_ws.
// Detects int64 vs int32 storage of invcol: for little-endian int64 values
// < 2^32, every odd int32 word is 0; an int32 permutation of 0..11007 has at
// most one zero among the 16 sampled odd words.
// ---------------------------------------------------------------------------
__global__ void build_jgrp_kernel(const int32_t* __restrict__ invcol_raw,
                                  uint8_t* __restrict__ jgrp) {
    bool is64 = true;
    #pragma unroll
    for (int i = 1; i < 32; i += 2) {
        if (invcol_raw[i] != 0) { is64 = false; }
    }
    int k = blockIdx.x * blockDim.x + threadIdx.x;
    if (k < COLS) {
        int j = is64 ? invcol_raw[2 * k] : invcol_raw[k];
        jgrp[k] = (uint8_t)(j >> 7);
    }
}

// ---------------------------------------------------------------------------
// Kernel 2: elementwise quant-dequant, f64-round-faithful.
// out[r,k] = (clip(round(x/s) + rzp, 0, qmax) - rzp) * s
//          = clip(round(x/s), -rzp, qmax - rzp) * s   (exact: ints < 2^24)
// The np oracle is evaluated in float64 (R1/R2 evidence: the exact f32 chain
// disagrees by one step at rare elements). Fast path: f32 correctly-rounded
// divide + rintf. If the quotient sits within ~4 ulp of a half-integer
// boundary (where f32 and f64 rint can disagree), redo the quotient + rint
// in double. Guard rate ~1e-5 of elements -> negligible divergence.
// ---------------------------------------------------------------------------
__device__ __forceinline__ float qround(float v, float s) {
    float q = __fdiv_rn(v, s);
    float t = rintf(q);
    float d = fabsf(fabsf(q - t) - 0.5f);          // distance to nearest x.5
    if (d <= fabsf(q) * 4.8e-7f + 1e-30f) {        // ~4 ulp guard band
        double qd = (double)v / (double)s;
        t = (float)rint(qd);                        // |t| < 2^24: cast exact
    }
    return t;
}

__global__ __launch_bounds__(256) void quantdeq_kernel(
        const float*   __restrict__ x,
        const float*   __restrict__ scale,
        const float*   __restrict__ zp,
        const int32_t* __restrict__ qmax,
        const uint8_t* __restrict__ jgrp,
        float*         __restrict__ out) {
    __shared__ float ls[GPR];
    __shared__ float llo[GPR];
    __shared__ float lhi[GPR];

    const int row = blockIdx.x;
    const int tid = threadIdx.x;

    if (tid < GPR) {
        const int gi = row * GPR + tid;
        float s   = fminf(fmaxf(scale[gi], 1e-4f), 1e4f);
        float qmf = (float)qmax[gi];
        float rzp = fminf(fmaxf(rintf(zp[gi]), 0.0f), qmf);
        ls[tid]  = s;
        llo[tid] = -rzp;
        lhi[tid] = qmf - rzp;
    }
    __syncthreads();

    const float4* __restrict__ xrow = reinterpret_cast<const float4*>(x + (size_t)row * COLS);
    float4*       __restrict__ orow = reinterpret_cast<float4*>(out + (size_t)row * COLS);
    const uchar4* __restrict__ jg4  = reinterpret_cast<const uchar4*>(jgrp);

    for (int t = tid; t < COLS / 4; t += 256) {
        float4 v = xrow[t];
        uchar4 g = jg4[t];
        float4 o;
        {
            float s = ls[g.x];
            float q = qround(v.x, s);
            q = fminf(fmaxf(q, llo[g.x]), lhi[g.x]);
            o.x = __fmul_rn(q, s);
        }
        {
            float s = ls[g.y];
            float q = qround(v.y, s);
            q = fminf(fmaxf(q, llo[g.y]), lhi[g.y]);
            o.y = __fmul_rn(q, s);
        }
        {
            float s = ls[g.z];
            float q = qround(v.z, s);
            q = fminf(fmaxf(q, llo[g.z]), lhi[g.z]);
            o.z = __fmul_rn(q, s);
        }
        {
            float s = ls[g.w];
            float q = qround(v.w, s);
            q = fminf(fmaxf(q, llo[g.w]), lhi[g.w]);
            o.w = __fmul_rn(q, s);
        }
        orow[t] = o;
    }
}

// ---------------------------------------------------------------------------
// Launch
// Inputs (setup_inputs order): 0=x, 1=scale, 2=zero_point, 3=qmax,
//                              4=col_order (unused), 5=invcol
// ---------------------------------------------------------------------------
extern "C" void kernel_launch(void* const* d_in, const int* in_sizes, int n_in,
                              void* d_out, int out_size, void* d_ws, size_t ws_size,
                              hipStream_t stream) {
    const float*   x     = (const float*)d_in[0];
    const float*   scale = (const float*)d_in[1];
    const float*   zp    = (const float*)d_in[2];
    const int32_t* qmax  = (const int32_t*)d_in[3];
    const int32_t* invc  = (const int32_t*)d_in[5];
    float*         out   = (float*)d_out;
    uint8_t*       jgrp  = (uint8_t*)d_ws;   // 11008 bytes

    build_jgrp_kernel<<<(COLS + 255) / 256, 256, 0, stream>>>(invc, jgrp);
    quantdeq_kernel<<<ROWS, 256, 0, stream>>>(x, scale, zp, qmax, jgrp, out);
}

// Round 5
// 65.252 us; speedup vs baseline: 1.3060x; 1.3060x over previous
//
#include <hip/hip_runtime.h>
#include <stdint.h>
#include <math.h>

#define ROWS 4096
#define COLS 11008
#define GPR  86            // groups per row
#define NV   (COLS / 4)    // 2752 float4 per row

typedef float f32x4 __attribute__((ext_vector_type(4)));

// ---------------------------------------------------------------------------
// Kernel 1: build jgrp[k] = invcol[k] >> 7  (uint8, 0..85) into d_ws.
// int64-vs-int32 detection: for little-endian int64 values < 2^32 every odd
// int32 word is 0; an int32 permutation of 0..11007 has at most one zero
// among the 16 sampled odd words.
// ---------------------------------------------------------------------------
__global__ void build_jgrp_kernel(const int32_t* __restrict__ invcol_raw,
                                  uint8_t* __restrict__ jgrp) {
    bool is64 = true;
    #pragma unroll
    for (int i = 1; i < 32; i += 2) {
        if (invcol_raw[i] != 0) { is64 = false; }
    }
    int k = blockIdx.x * blockDim.x + threadIdx.x;
    if (k < COLS) {
        int j = is64 ? invcol_raw[2 * k] : invcol_raw[k];
        jgrp[k] = (uint8_t)(j >> 7);
    }
}

// ---------------------------------------------------------------------------
// Kernel 2: elementwise quant-dequant, f64-round-faithful, rcp fast path.
//   out = clip(round(x/s), -rzp, qmax-rzp) * s     (exact: ints < 2^24)
// Fast path: q0 = x * (1/s), both correctly rounded -> q0 within ~2.6 ulp of
// the f64 quotient. If q0 is within a ~10-ulp band of a half-integer boundary
// (fire rate ~7e-6), redo quotient+rint in f64 (this exact fallback gave
// absmax 0.0 in R3). Params packed as float4 {s, 1/s, -rzp, qmax-rzp} in LDS
// -> one ds_read_b128 per element instead of 3 ds_read_b32.
// Next iteration's x/jgrp loads are software-pipelined over current compute.
// Output stored nontemporally so the write stream doesn't evict x from L3.
// ---------------------------------------------------------------------------
__device__ __forceinline__ float qdq(float v, float4 p) {
    float q0 = __fmul_rn(v, p.y);
    float t  = rintf(q0);
    float d  = fabsf(fabsf(q0 - t) - 0.5f);         // distance to nearest x.5
    if (d <= fabsf(q0) * 1.2e-6f + 1e-30f) {        // ~10 ulp guard band
        t = (float)rint((double)v / (double)p.x);   // |t| < 2^24: cast exact
    }
    t = fminf(fmaxf(t, p.z), p.w);
    return __fmul_rn(t, p.x);
}

__global__ __launch_bounds__(256) void quantdeq_kernel(
        const float*   __restrict__ x,
        const float*   __restrict__ scale,
        const float*   __restrict__ zp,
        const int32_t* __restrict__ qmax,
        const uint8_t* __restrict__ jgrp,
        float*         __restrict__ out) {
    __shared__ float4 lp[GPR];

    const int row = blockIdx.x;
    const int tid = threadIdx.x;

    if (tid < GPR) {
        const int gi = row * GPR + tid;
        float s   = fminf(fmaxf(scale[gi], 1e-4f), 1e4f);
        float rs  = __fdiv_rn(1.0f, s);
        float qmf = (float)qmax[gi];
        float rzp = fminf(fmaxf(rintf(zp[gi]), 0.0f), qmf);
        lp[tid] = make_float4(s, rs, -rzp, qmf - rzp);
    }
    __syncthreads();

    const float4* __restrict__ xrow = reinterpret_cast<const float4*>(x + (size_t)row * COLS);
    f32x4*        __restrict__ orow = reinterpret_cast<f32x4*>(out + (size_t)row * COLS);
    const uchar4* __restrict__ jg4  = reinterpret_cast<const uchar4*>(jgrp);

    // software-pipelined: load (t+256) while computing t
    int    t = tid;                 // 256 <= NV, so every thread has work
    float4 v = xrow[t];
    uchar4 g = jg4[t];
    for (int tn = t + 256; tn < NV; tn += 256) {
        float4 vn = xrow[tn];
        uchar4 gn = jg4[tn];
        f32x4 o;
        o.x = qdq(v.x, lp[g.x]);
        o.y = qdq(v.y, lp[g.y]);
        o.z = qdq(v.z, lp[g.z]);
        o.w = qdq(v.w, lp[g.w]);
        __builtin_nontemporal_store(o, &orow[t]);
        t = tn; v = vn; g = gn;
    }
    {
        f32x4 o;
        o.x = qdq(v.x, lp[g.x]);
        o.y = qdq(v.y, lp[g.y]);
        o.z = qdq(v.z, lp[g.z]);
        o.w = qdq(v.w, lp[g.w]);
        __builtin_nontemporal_store(o, &orow[t]);
    }
}

// ---------------------------------------------------------------------------
// Launch
// Inputs (setup_inputs order): 0=x, 1=scale, 2=zero_point, 3=qmax,
//                              4=col_order (unused), 5=invcol
// ---------------------------------------------------------------------------
extern "C" void kernel_launch(void* const* d_in, const int* in_sizes, int n_in,
                              void* d_out, int out_size, void* d_ws, size_t ws_size,
                              hipStream_t stream) {
    const float*   x     = (const float*)d_in[0];
    const float*   scale = (const float*)d_in[1];
    const float*   zp    = (const float*)d_in[2];
    const int32_t* qmax  = (const int32_t*)d_in[3];
    const int32_t* invc  = (const int32_t*)d_in[5];
    float*         out   = (float*)d_out;
    uint8_t*       jgrp  = (uint8_t*)d_ws;   // 11008 bytes

    build_jgrp_kernel<<<(COLS + 255) / 256, 256, 0, stream>>>(invc, jgrp);
    quantdeq_kernel<<<ROWS, 256, 0, stream>>>(x, scale, zp, qmax, jgrp, out);
}